// Round 7
// baseline (119.473 us; speedup 1.0000x reference)
//
#include <hip/hip_runtime.h>

// SA_Head: B=4, S=4096, E=256, H=64
//   out = softmax((emb@wq)(emb@wk)^T / 16) (emb@wv)
// R11: occupancy + pipeline depth on the R10 LDS-staged attn.
//  - split-K x4 (1024 blocks, 16 tt): staging traffic invariant, but
//    4 blocks/CU -> 4 waves/SIMD (was 2).  LDS 33KB*4=132 <= 160KB.
//  - depth-2 staging: two named reg sets; loads for tile t+2 issued before
//    ds_write of tile t+1 -> compiler emits counted vmcnt(4), never 0 (T4).
//  - proj: 32 rows/block (512 blocks), each wt fragment feeds 2 row-groups
//    -> 2x MFMA per staged/loaded byte.
//  - reduce: 4-split pure-f4 stream (po 16MB).
// (R10: K/V tiles staged in LDS, XOR-swizzled chunk^=row&7, T14 split
//  staging, one barrier/tt. R6 base: XCD swizzle, no-max softmax |s|<=4,
//  S^T-form QK keeps P in registers, V pre-transposed vbt[h][s].)

typedef short short4v __attribute__((ext_vector_type(4)));
typedef short short8v __attribute__((ext_vector_type(8)));
typedef float floatx4 __attribute__((ext_vector_type(4)));
typedef unsigned short u16;
typedef unsigned int u32;

#define SEQ 4096
#define EMB 256
#define HD 64
#define PADA 264   // u16 stride for proj A tile
#define OSTR 68    // f32 stride for attn epilogue O[q][h] tile

static __device__ __forceinline__ u16 f2bf(float x) {
    union { float f; unsigned u; } v; v.f = x;
    unsigned r = v.u + 0x7FFFu + ((v.u >> 16) & 1u);
    return (u16)(r >> 16);
}

static __device__ __forceinline__ u32 cvt_pk_bf16(float a, float b) {
    u32 r;
    asm("v_cvt_pk_bf16_f32 %0, %1, %2" : "=v"(r) : "v"(a), "v"(b));
    return r;
}

static __device__ __forceinline__ short4v pack_bf4(float a, float b, float c, float d) {
    union { u32 u[2]; short4v s; } x;
    x.u[0] = cvt_pk_bf16(a, b);
    x.u[1] = cvt_pk_bf16(c, d);
    return x.s;
}

// ---------------- W prep: fragment-major Wt --------------------------------------
__global__ __launch_bounds__(256) void prep_w(
    const float* __restrict__ wk, const float* __restrict__ wq, const float* __restrict__ wv,
    u16* __restrict__ wt) {
    const int nt = blockIdx.x;   // 0..11
    const int t = threadIdx.x;
#pragma unroll
    for (int ss = 0; ss < 2; ++ss) {
        int slot = t + ss * 256;          // 0..511
        int kc = slot >> 6, lane = slot & 63;
        int ln15 = lane & 15, lq = lane >> 4;
        int cg = nt * 16 + ln15;
        int mat = cg >> 6, col = cg & 63;
        const float* W = (mat == 0) ? wq : (mat == 1) ? wk : wv;
        const float s = (mat == 0) ? 0.0625f * 1.44269504088896f : 1.0f;
        u32 w4[4];
#pragma unroll
        for (int p = 0; p < 2; ++p) {
#pragma unroll
            for (int d = 0; d < 2; ++d) {
                int e0 = kc * 32 + lq * 8 + p * 4 + d * 2;
                u16 lo = f2bf(W[(e0 + 0) * HD + col] * s);
                u16 hi = f2bf(W[(e0 + 1) * HD + col] * s);
                w4[p * 2 + d] = (u32)lo | ((u32)hi << 16);
            }
        }
        u32* dst = (u32*)wt + ((size_t)(nt * 8 + kc) * 64 + lane) * 4;
        *(uint4*)dst = make_uint4(w4[0], w4[1], w4[2], w4[3]);
    }
}

// ---------------- projection GEMM: [16384,256]@[256,192] bf16 MFMA ----------------
// grid 512 x 256; 32 rows/block; wave w covers ntiles 3w..3w+2 for both
// 16-row groups (each wt fragment feeds 2 MFMAs); v -> vbt[h][s].
__global__ __launch_bounds__(256) void proj_mfma(
    const float* __restrict__ emb, const u16* __restrict__ wt,
    u16* __restrict__ qb, u16* __restrict__ kb, u16* __restrict__ vbt) {
    __shared__ u16 a_s[32 * PADA];
    const int t = threadIdx.x;
    const int lane = t & 63;
    const int wave = t >> 6;
    const int ln15 = lane & 15;
    const int lq = lane >> 4;
    const size_t row0 = (size_t)blockIdx.x * 32;

    // coalesced staging: flat float4 f = t + c*256 -> row f>>6, cols (f&63)*4
#pragma unroll
    for (int c = 0; c < 8; ++c) {
        int f = t + c * 256;
        int row = f >> 6, e4 = (f & 63) * 4;
        float4 v = *(const float4*)(emb + (row0 + row) * EMB + e4);
        u32 lo = cvt_pk_bf16(v.x, v.y);
        u32 hi = cvt_pk_bf16(v.z, v.w);
        *(uint2*)&a_s[row * PADA + e4] = make_uint2(lo, hi);
    }
    __syncthreads();

    floatx4 acc[2][3];
#pragma unroll
    for (int rg = 0; rg < 2; ++rg)
#pragma unroll
        for (int j = 0; j < 3; ++j) {
            floatx4 z = { 0.f, 0.f, 0.f, 0.f };
            acc[rg][j] = z;
        }

#pragma unroll
    for (int kc = 0; kc < 8; ++kc) {
        short8v a0 = *(const short8v*)&a_s[ln15 * PADA + kc * 32 + lq * 8];
        short8v a1 = *(const short8v*)&a_s[(16 + ln15) * PADA + kc * 32 + lq * 8];
#pragma unroll
        for (int j = 0; j < 3; ++j) {
            short8v b = *(const short8v*)(wt + (((size_t)(wave * 3 + j) * 8 + kc) * 64 + lane) * 8);
            acc[0][j] = __builtin_amdgcn_mfma_f32_16x16x32_bf16(a0, b, acc[0][j], 0, 0, 0);
            acc[1][j] = __builtin_amdgcn_mfma_f32_16x16x32_bf16(a1, b, acc[1][j], 0, 0, 0);
        }
    }

#pragma unroll
    for (int rg = 0; rg < 2; ++rg) {
        const size_t row0g = row0 + rg * 16;
#pragma unroll
        for (int j = 0; j < 3; ++j) {
            int cg = (wave * 3 + j) * 16 + ln15;
            int mat = cg >> 6, col = cg & 63;
            if (mat < 2) {
                u16* O = (mat == 0) ? qb : kb;
#pragma unroll
                for (int r = 0; r < 4; ++r)
                    O[(row0g + lq * 4 + r) * HD + col] = f2bf(acc[rg][j][r]);
            } else {
                u32 lo = cvt_pk_bf16(acc[rg][j][0], acc[rg][j][1]);
                u32 hi = cvt_pk_bf16(acc[rg][j][2], acc[rg][j][3]);
                size_t bidx = row0g >> 12;
                size_t sl = (row0g & 4095) + lq * 4;
                *(uint2*)&vbt[(bidx * 64 + col) * SEQ + sl] = make_uint2(lo, hi);
            }
        }
    }
}

// ---------------- flash attention: LDS-staged tiles, split-K x4, depth-2 ----------
// part = b*256 + qt*4 + split; 4 waves; wave w owns keys [tile + 16w, +16).
// Per tt: K[64 keys][64 dims] and V^T[64 h][64 keys] staged in LDS
// (coalesced, XOR-swizzled chunk^=row&7); S^T = K.Q^T (16x16x32), P = exp2
// in-reg, O^T += V^T.P (16x16x16).  Two reg staging sets: loads for tile
// t+2 issued before ds_write of t+1 -> counted vmcnt, never 0.

struct AttnCtx {
    int ksw_lo, ksw_hi, voff, ln15, lq;
};

static __device__ __forceinline__ void attn_compute(
    const u16* __restrict__ kt, const u16* __restrict__ vt, const AttnCtx& cx,
    const short8v (&qf)[4][2], floatx4 (&oacc)[4][4], float (&lacc)[4]) {
    // V^T A-frags from LDS (8B each, swizzled)
    short4v vf[4];
#pragma unroll
    for (int ht = 0; ht < 4; ++ht)
        vf[ht] = *(const short4v*)(vt + (ht * 16 + cx.ln15) * 64 + cx.voff);

    // K A-frags from LDS (16B, swizzled)
    short8v k0 = *(const short8v*)(kt + cx.ksw_lo);
    short8v k1 = *(const short8v*)(kt + cx.ksw_hi);

    // S^T tiles: D[m=key][n=qrow]
    floatx4 s[4];
    __builtin_amdgcn_s_setprio(1);
#pragma unroll
    for (int nt = 0; nt < 4; ++nt) {
        floatx4 z = { 0.f, 0.f, 0.f, 0.f };
        s[nt] = __builtin_amdgcn_mfma_f32_16x16x32_bf16(k0, qf[nt][0], z, 0, 0, 0);
        s[nt] = __builtin_amdgcn_mfma_f32_16x16x32_bf16(k1, qf[nt][1], s[nt], 0, 0, 0);
    }
    __builtin_amdgcn_s_setprio(0);

    // P = exp2(S^T): C-layout == 16x16x16 B-layout, stays in registers
    short4v pf[4];
#pragma unroll
    for (int nt = 0; nt < 4; ++nt) {
        float p0 = __builtin_amdgcn_exp2f(s[nt][0]);
        float p1 = __builtin_amdgcn_exp2f(s[nt][1]);
        float p2 = __builtin_amdgcn_exp2f(s[nt][2]);
        float p3 = __builtin_amdgcn_exp2f(s[nt][3]);
        lacc[nt] += (p0 + p1) + (p2 + p3);
        pf[nt] = pack_bf4(p0, p1, p2, p3);
    }

    // O^T += V^T . P
    __builtin_amdgcn_s_setprio(1);
#pragma unroll
    for (int ht = 0; ht < 4; ++ht)
#pragma unroll
        for (int nt = 0; nt < 4; ++nt)
            oacc[ht][nt] = __builtin_amdgcn_mfma_f32_16x16x16bf16_1k(
                vf[ht], pf[nt], oacc[ht][nt], 0, 0, 0);
    __builtin_amdgcn_s_setprio(0);
}

__global__ __launch_bounds__(256) void attn_kernel(
    const u16* __restrict__ qb, const u16* __restrict__ kb, const u16* __restrict__ vbt,
    float* __restrict__ po, float* __restrict__ pml) {
    // smem[buf*2+0] = K tile, smem[buf*2+1] = V tile; each 64 rows x 128B.
    // 16B chunk c of row r stored at chunk (c ^ (r&7)).  Re-used as ored[].
    __shared__ __align__(16) u16 smem[4][64 * 64];
    __shared__ float lred[4 * 64];

    const int t = threadIdx.x;
    const int lane = t & 63;
    const int wave = t >> 6;
    const int ln15 = lane & 15;
    const int lq = lane >> 4;

    // XCD-aware swizzle (1024 blocks, 1024%8==0 -> bijective)
    const int part = ((blockIdx.x & 7) << 7) | (blockIdx.x >> 3);
    const int b = part >> 8;
    const int qt = (part >> 2) & 63;
    const int split = part & 3;
    const int q0 = qt * 64;

    const u16* __restrict__ qpb = qb + ((size_t)b * SEQ + q0) * HD;
    const u16* __restrict__ kpb = kb + (size_t)b * SEQ * HD;
    const u16* __restrict__ vpb = vbt + (size_t)b * HD * SEQ;

    // Q B-frags (loop-invariant)
    short8v qf[4][2];
#pragma unroll
    for (int nt = 0; nt < 4; ++nt)
#pragma unroll
        for (int h = 0; h < 2; ++h)
            qf[nt][h] = *(const short8v*)(qpb + (size_t)(nt * 16 + ln15) * HD + h * 32 + lq * 8);

    floatx4 oacc[4][4];
#pragma unroll
    for (int ht = 0; ht < 4; ++ht)
#pragma unroll
        for (int nt = 0; nt < 4; ++nt) {
            floatx4 z = { 0.f, 0.f, 0.f, 0.f };
            oacc[ht][nt] = z;
        }
    float lacc[4] = { 0.f, 0.f, 0.f, 0.f };

    // staging geometry: flat f = t (+256): row = f>>3, chunk = f&7 (16B units).
    const int r0 = t >> 3, c0 = t & 7;
    const int r1 = (t + 256) >> 3;
    const int sw0 = r0 * 64 + ((c0 ^ (r0 & 7)) * 8);
    const int sw1 = r1 * 64 + ((c0 ^ (r1 & 7)) * 8);

    AttnCtx cx;
    cx.ln15 = ln15; cx.lq = lq;
    const int krow = wave * 16 + ln15;
    cx.ksw_lo = krow * 64 + (((0 + lq) ^ (ln15 & 7)) * 8);
    cx.ksw_hi = krow * 64 + (((4 + lq) ^ (ln15 & 7)) * 8);
    const int vch = wave * 2 + (lq >> 1);
    cx.voff = ((vch ^ (ln15 & 7)) * 8) + (lq & 1) * 4;

    uint4 kraA, krbA, vraA, vrbA;   // staging reg set A (even tiles)
    uint4 kraB, krbB, vraB, vrbB;   // staging reg set B (odd tiles)

#define LOADT(n, KA, KB, VA, VB) { const int kwb = (split * 16 + (n)) * 64;            \
        KA = *(const uint4*)(kpb + (size_t)(kwb + r0) * HD + c0 * 8);                  \
        KB = *(const uint4*)(kpb + (size_t)(kwb + r1) * HD + c0 * 8);                  \
        VA = *(const uint4*)(vpb + (size_t)r0 * SEQ + kwb + c0 * 8);                   \
        VB = *(const uint4*)(vpb + (size_t)r1 * SEQ + kwb + c0 * 8); }
#define WRITET(B, KA, KB, VA, VB) { u16* kt_ = &smem[(B) * 2][0]; u16* vt_ = &smem[(B) * 2 + 1][0]; \
        *(uint4*)(kt_ + sw0) = KA; *(uint4*)(kt_ + sw1) = KB;                          \
        *(uint4*)(vt_ + sw0) = VA; *(uint4*)(vt_ + sw1) = VB; }

    // prologue: T0 -> set A -> buf0; T1 -> set B (in flight across the write)
    LOADT(0, kraA, krbA, vraA, vrbA);
    LOADT(1, kraB, krbB, vraB, vrbB);
    WRITET(0, kraA, krbA, vraA, vrbA);
    __syncthreads();

#pragma unroll 1
    for (int th = 0; th < 8; ++th) {
        // even tt = 2th: compute buf0; T(2th+1) (set B) -> buf1
        if (th < 7) LOADT(2 * th + 2, kraA, krbA, vraA, vrbA);
        attn_compute(&smem[0][0], &smem[1][0], cx, qf, oacc, lacc);
        WRITET(1, kraB, krbB, vraB, vrbB);
        __syncthreads();
        // odd tt = 2th+1: compute buf1; T(2th+2) (set A) -> buf0
        if (th < 7) {
            LOADT(2 * th + 3, kraB, krbB, vraB, vrbB);
        }
        attn_compute(&smem[2][0], &smem[3][0], cx, qf, oacc, lacc);
        if (th < 7) {
            WRITET(0, kraA, krbA, vraA, vrbA);
        }
        __syncthreads();
    }
#undef LOADT
#undef WRITET

    // ---- epilogue: cross-wave reduce (once per block) ----
#pragma unroll
    for (int nt = 0; nt < 4; ++nt) {
        lacc[nt] += __shfl_xor(lacc[nt], 16);
        lacc[nt] += __shfl_xor(lacc[nt], 32);
    }
    if (lq == 0) {
#pragma unroll
        for (int nt = 0; nt < 4; ++nt)
            lred[wave * 64 + nt * 16 + ln15] = lacc[nt];
    }

    // O[q][h] reduce in LDS (aliases staging buffers; loop's final barrier
    // guarantees all tile reads done).
    float* ored = (float*)&smem[0][0];
    for (int s4 = 0; s4 < 4; ++s4) {
        if (wave == s4) {
#pragma unroll
            for (int nt = 0; nt < 4; ++nt)
#pragma unroll
                for (int ht = 0; ht < 4; ++ht) {
                    int idx = (nt * 16 + ln15) * OSTR + ht * 16 + lq * 4;
                    if (s4 == 0) {
                        *(floatx4*)&ored[idx] = oacc[ht][nt];
                    } else {
                        floatx4 old = *(floatx4*)&ored[idx];
                        old += oacc[ht][nt];
                        *(floatx4*)&ored[idx] = old;
                    }
                }
        }
        __syncthreads();
    }

    // write po[part][q][h] (coalesced float4) and combined l
    float* __restrict__ pob = po + (size_t)part * 4096;
#pragma unroll
    for (int i = 0; i < 4; ++i) {
        int f4 = t + i * 256;             // 0..1023
        int q = f4 >> 4, h4 = (f4 & 15) * 4;
        *(float4*)&pob[q * HD + h4] = *(float4*)&ored[q * OSTR + h4];
    }
    if (t < 64)
        pml[part * 64 + t] = lred[t] + lred[64 + t] + lred[128 + t] + lred[192 + t];
}

// ---------------- split reduction: sum 4 splits, normalize (pure f4 stream) -------
__global__ __launch_bounds__(256) void reduce_kernel(
    const float* __restrict__ po, const float* __restrict__ pml,
    float* __restrict__ out) {
    __shared__ float ls[64];
    const int t = threadIdx.x;
    const int part0 = blockIdx.x * 4;
    const int bq = blockIdx.x;           // b = bq>>6, qt = bq&63

    if (t < 64)
        ls[t] = pml[(part0 + 0) * 64 + t] + pml[(part0 + 1) * 64 + t]
              + pml[(part0 + 2) * 64 + t] + pml[(part0 + 3) * 64 + t];
    __syncthreads();

    const float* __restrict__ p0 = po + (size_t)(part0 + 0) * 4096;
    const float* __restrict__ p1 = po + (size_t)(part0 + 1) * 4096;
    const float* __restrict__ p2 = po + (size_t)(part0 + 2) * 4096;
    const float* __restrict__ p3 = po + (size_t)(part0 + 3) * 4096;
    float* __restrict__ ob = out + (((size_t)(bq >> 6) * SEQ + (size_t)(bq & 63) * 64)) * HD;

#pragma unroll
    for (int i = 0; i < 4; ++i) {
        int f4 = t + i * 256;            // 0..1023
        int f = f4 * 4;
        int q = f4 >> 4;
        float4 a = *(const float4*)&p0[f];
        float4 c = *(const float4*)&p1[f];
        float4 d = *(const float4*)&p2[f];
        float4 e = *(const float4*)&p3[f];
        float inv = 1.0f / ls[q];
        float4 r;
        r.x = (a.x + c.x + d.x + e.x) * inv;
        r.y = (a.y + c.y + d.y + e.y) * inv;
        r.z = (a.z + c.z + d.z + e.z) * inv;
        r.w = (a.w + c.w + d.w + e.w) * inv;
        *(float4*)&ob[f] = r;
    }
}

extern "C" void kernel_launch(void* const* d_in, const int* in_sizes, int n_in,
                              void* d_out, int out_size, void* d_ws, size_t ws_size,
                              hipStream_t stream) {
    const float* emb = (const float*)d_in[0];
    const float* wk  = (const float*)d_in[1];
    const float* wq  = (const float*)d_in[2];
    const float* wv  = (const float*)d_in[3];

    // ws: qb 2M @0, kb 2M @2M, vbt 2M @4M, wt 96K @6M, po 16M @6.25M, pml 256K @22.25M
    u16* qb  = (u16*)d_ws;
    u16* kb  = (u16*)((char*)d_ws + (size_t)2 * 1024 * 1024);
    u16* vbt = (u16*)((char*)d_ws + (size_t)4 * 1024 * 1024);
    u16* wt  = (u16*)((char*)d_ws + (size_t)6 * 1024 * 1024);
    float* po  = (float*)((char*)d_ws + (size_t)6 * 1024 * 1024 + 256 * 1024);
    float* pml = (float*)((char*)d_ws + (size_t)22 * 1024 * 1024 + 256 * 1024);
    float* out = (float*)d_out;

    prep_w<<<12, 256, 0, stream>>>(wk, wq, wv, wt);
    proj_mfma<<<512, 256, 0, stream>>>(emb, wt, qb, kb, vbt);
    attn_kernel<<<1024, 256, 0, stream>>>(qb, kb, vbt, po, pml);
    reduce_kernel<<<256, 256, 0, stream>>>(po, pml, out);
}

// Round 8
// 114.658 us; speedup vs baseline: 1.0420x; 1.0420x over previous
//
#include <hip/hip_runtime.h>

// SA_Head: B=4, S=4096, E=256, H=64
//   out = softmax((emb@wq)(emb@wk)^T / 16) (emb@wv)
// R12: halve staging re-read traffic. R10's attn staged 16KB K/V tiles that
// served only 64 q (256MB of L2/L3 re-reads = the wall). Now each block
// covers 128 q: 4 waves x (32 q x ALL 64 keys) per tile -> 128MB traffic,
// half the barriers (16 tt), and the cross-wave O-reduce vanishes (each
// wave owns all keys for its q-rows: direct po write, in-wave l-reduce).
// Split-K x4 keeps grid 512 = 2 blocks/CU. proj/prep = R10 verbatim.
// (R10: LDS-staged K/V, XOR-swizzle chunk^=row&7, load-top/write-bottom,
//  one barrier/tt. Base: XCD swizzle, no-max softmax |s|<=4, S^T-form QK
//  keeps P in registers, V pre-transposed vbt[h][s].)

typedef short short4v __attribute__((ext_vector_type(4)));
typedef short short8v __attribute__((ext_vector_type(8)));
typedef float floatx4 __attribute__((ext_vector_type(4)));
typedef unsigned short u16;
typedef unsigned int u32;

#define SEQ 4096
#define EMB 256
#define HD 64
#define PADA 264   // u16 stride for proj A tile

static __device__ __forceinline__ u16 f2bf(float x) {
    union { float f; unsigned u; } v; v.f = x;
    unsigned r = v.u + 0x7FFFu + ((v.u >> 16) & 1u);
    return (u16)(r >> 16);
}

static __device__ __forceinline__ u32 cvt_pk_bf16(float a, float b) {
    u32 r;
    asm("v_cvt_pk_bf16_f32 %0, %1, %2" : "=v"(r) : "v"(a), "v"(b));
    return r;
}

static __device__ __forceinline__ short4v pack_bf4(float a, float b, float c, float d) {
    union { u32 u[2]; short4v s; } x;
    x.u[0] = cvt_pk_bf16(a, b);
    x.u[1] = cvt_pk_bf16(c, d);
    return x.s;
}

// ---------------- W prep: fragment-major Wt --------------------------------------
__global__ __launch_bounds__(256) void prep_w(
    const float* __restrict__ wk, const float* __restrict__ wq, const float* __restrict__ wv,
    u16* __restrict__ wt) {
    const int nt = blockIdx.x;   // 0..11
    const int t = threadIdx.x;
#pragma unroll
    for (int ss = 0; ss < 2; ++ss) {
        int slot = t + ss * 256;          // 0..511
        int kc = slot >> 6, lane = slot & 63;
        int ln15 = lane & 15, lq = lane >> 4;
        int cg = nt * 16 + ln15;
        int mat = cg >> 6, col = cg & 63;
        const float* W = (mat == 0) ? wq : (mat == 1) ? wk : wv;
        const float s = (mat == 0) ? 0.0625f * 1.44269504088896f : 1.0f;
        u32 w4[4];
#pragma unroll
        for (int p = 0; p < 2; ++p) {
#pragma unroll
            for (int d = 0; d < 2; ++d) {
                int e0 = kc * 32 + lq * 8 + p * 4 + d * 2;
                u16 lo = f2bf(W[(e0 + 0) * HD + col] * s);
                u16 hi = f2bf(W[(e0 + 1) * HD + col] * s);
                w4[p * 2 + d] = (u32)lo | ((u32)hi << 16);
            }
        }
        u32* dst = (u32*)wt + ((size_t)(nt * 8 + kc) * 64 + lane) * 4;
        *(uint4*)dst = make_uint4(w4[0], w4[1], w4[2], w4[3]);
    }
}

// ---------------- projection GEMM: [16384,256]@[256,192] bf16 MFMA ----------------
__global__ __launch_bounds__(256) void proj_mfma(
    const float* __restrict__ emb, const u16* __restrict__ wt,
    u16* __restrict__ qb, u16* __restrict__ kb, u16* __restrict__ vbt) {
    __shared__ u16 a_s[16 * PADA];
    const int t = threadIdx.x;
    const int lane = t & 63;
    const int wave = t >> 6;
    const int ln15 = lane & 15;
    const int lq = lane >> 4;
    const size_t row0 = (size_t)blockIdx.x * 16;

#pragma unroll
    for (int c = 0; c < 4; ++c) {
        int f = t + c * 256;
        int row = f >> 6, e4 = (f & 63) * 4;
        float4 v = *(const float4*)(emb + (row0 + row) * EMB + e4);
        u32 lo = cvt_pk_bf16(v.x, v.y);
        u32 hi = cvt_pk_bf16(v.z, v.w);
        *(uint2*)&a_s[row * PADA + e4] = make_uint2(lo, hi);
    }
    __syncthreads();

    floatx4 acc[3];
#pragma unroll
    for (int j = 0; j < 3; ++j) {
        floatx4 z = { 0.f, 0.f, 0.f, 0.f };
        acc[j] = z;
    }

#pragma unroll
    for (int kc = 0; kc < 8; ++kc) {
        short8v a = *(const short8v*)&a_s[ln15 * PADA + kc * 32 + lq * 8];
#pragma unroll
        for (int j = 0; j < 3; ++j) {
            short8v b = *(const short8v*)(wt + (((size_t)(wave * 3 + j) * 8 + kc) * 64 + lane) * 8);
            acc[j] = __builtin_amdgcn_mfma_f32_16x16x32_bf16(a, b, acc[j], 0, 0, 0);
        }
    }

#pragma unroll
    for (int j = 0; j < 3; ++j) {
        int cg = (wave * 3 + j) * 16 + ln15;
        int mat = cg >> 6, col = cg & 63;
        if (mat < 2) {
            u16* O = (mat == 0) ? qb : kb;
#pragma unroll
            for (int r = 0; r < 4; ++r)
                O[(row0 + lq * 4 + r) * HD + col] = f2bf(acc[j][r]);
        } else {
            u32 lo = cvt_pk_bf16(acc[j][0], acc[j][1]);
            u32 hi = cvt_pk_bf16(acc[j][2], acc[j][3]);
            size_t bidx = row0 >> 12;
            size_t sl = (row0 & 4095) + lq * 4;
            *(uint2*)&vbt[(bidx * 64 + col) * SEQ + sl] = make_uint2(lo, hi);
        }
    }
}

// ---------------- flash attention: LDS-staged tiles, 128q blocks, split-K x4 ------
// part = b*128 + qblk*4 + split; 4 waves; wave w owns q [q0+32w, +32) and
// ALL 64 keys of each staged tile.  Per tt: K[64k][64d], V^T[64h][64k] in
// LDS (coalesced, chunk^=row&7 swizzle); per 16-key subtile kt:
// S^T = K.Q^T (16x16x32), P = exp2 in-reg, O^T += V^T.P (16x16x16).
// No cross-wave O reduce: wave writes its finished 32q x 64h to po.

__global__ __launch_bounds__(256) void attn_kernel(
    const u16* __restrict__ qb, const u16* __restrict__ kb, const u16* __restrict__ vbt,
    float* __restrict__ po, float* __restrict__ pml) {
    __shared__ __align__(16) u16 smem[4][64 * 64];   // [buf*2+{K,V}][64 rows x 128B]

    const int t = threadIdx.x;
    const int lane = t & 63;
    const int wave = t >> 6;
    const int ln15 = lane & 15;
    const int lq = lane >> 4;

    // XCD-aware swizzle (512 blocks, 512%8==0 -> bijective)
    const int part = ((blockIdx.x & 7) << 6) | (blockIdx.x >> 3);
    const int b = part >> 7;
    const int qblk = (part >> 2) & 31;
    const int split = part & 3;
    const int q0 = qblk * 128;

    const u16* __restrict__ qpb = qb + ((size_t)b * SEQ + q0) * HD;
    const u16* __restrict__ kpb = kb + (size_t)b * SEQ * HD;
    const u16* __restrict__ vpb = vbt + (size_t)b * HD * SEQ;

    // Q B-frags (loop-invariant): wave's q rows = q0 + wave*32 + nt*16 + ln15
    short8v qf[2][2];
#pragma unroll
    for (int nt = 0; nt < 2; ++nt)
#pragma unroll
        for (int h = 0; h < 2; ++h)
            qf[nt][h] = *(const short8v*)(qpb + (size_t)(wave * 32 + nt * 16 + ln15) * HD + h * 32 + lq * 8);

    floatx4 oacc[4][2];
#pragma unroll
    for (int ht = 0; ht < 4; ++ht)
#pragma unroll
        for (int nt = 0; nt < 2; ++nt) {
            floatx4 z = { 0.f, 0.f, 0.f, 0.f };
            oacc[ht][nt] = z;
        }
    float lacc[2] = { 0.f, 0.f };

    // staging geometry: flat f = t (+256): row = f>>3, chunk = f&7 (16B units).
    const int r0 = t >> 3, c0 = t & 7, r1 = r0 + 32;
    const int sw0 = r0 * 64 + ((c0 ^ (r0 & 7)) * 8);
    const int sw1 = r1 * 64 + ((c0 ^ (r1 & 7)) * 8);

    // frag read offsets (u16 units); kt adds kt*1024 (rows) / chunk kt*2 (V)
    const int xk = ln15 & 7;
    const int ksw_lo = ln15 * 64 + ((lq ^ xk) * 8);
    const int ksw_hi = ln15 * 64 + (((4 + lq) ^ xk) * 8);
    const int vch0 = lq >> 1, vsub = (lq & 1) * 4;

    uint4 ka, kb4, va, vb4;
    {   // prologue: stage tile 0 into buf 0
        const int kwb = (split * 16) * 64;
        ka  = *(const uint4*)(kpb + (size_t)(kwb + r0) * HD + c0 * 8);
        kb4 = *(const uint4*)(kpb + (size_t)(kwb + r1) * HD + c0 * 8);
        va  = *(const uint4*)(vpb + (size_t)r0 * SEQ + kwb + c0 * 8);
        vb4 = *(const uint4*)(vpb + (size_t)r1 * SEQ + kwb + c0 * 8);
        *(uint4*)(&smem[0][0] + sw0) = ka;
        *(uint4*)(&smem[0][0] + sw1) = kb4;
        *(uint4*)(&smem[1][0] + sw0) = va;
        *(uint4*)(&smem[1][0] + sw1) = vb4;
    }
    __syncthreads();

#pragma unroll 1
    for (int tt = 0; tt < 16; ++tt) {
        const int buf = tt & 1;
        // issue next tile's global loads (latency hidden under compute)
        if (tt < 15) {
            const int kwb = (split * 16 + tt + 1) * 64;
            ka  = *(const uint4*)(kpb + (size_t)(kwb + r0) * HD + c0 * 8);
            kb4 = *(const uint4*)(kpb + (size_t)(kwb + r1) * HD + c0 * 8);
            va  = *(const uint4*)(vpb + (size_t)r0 * SEQ + kwb + c0 * 8);
            vb4 = *(const uint4*)(vpb + (size_t)r1 * SEQ + kwb + c0 * 8);
        }

        const u16* ktp = &smem[buf * 2 + 0][0];
        const u16* vtp = &smem[buf * 2 + 1][0];

        // 4 x 16-key subtiles; wave covers all of them for its 32 q
#pragma unroll
        for (int kt = 0; kt < 4; ++kt) {
            short8v k0 = *(const short8v*)(ktp + kt * 1024 + ksw_lo);
            short8v k1 = *(const short8v*)(ktp + kt * 1024 + ksw_hi);

            floatx4 s[2];
            __builtin_amdgcn_s_setprio(1);
#pragma unroll
            for (int nt = 0; nt < 2; ++nt) {
                floatx4 z = { 0.f, 0.f, 0.f, 0.f };
                s[nt] = __builtin_amdgcn_mfma_f32_16x16x32_bf16(k0, qf[nt][0], z, 0, 0, 0);
                s[nt] = __builtin_amdgcn_mfma_f32_16x16x32_bf16(k1, qf[nt][1], s[nt], 0, 0, 0);
            }
            __builtin_amdgcn_s_setprio(0);

            short4v pf[2];
#pragma unroll
            for (int nt = 0; nt < 2; ++nt) {
                float p0 = __builtin_amdgcn_exp2f(s[nt][0]);
                float p1 = __builtin_amdgcn_exp2f(s[nt][1]);
                float p2 = __builtin_amdgcn_exp2f(s[nt][2]);
                float p3 = __builtin_amdgcn_exp2f(s[nt][3]);
                lacc[nt] += (p0 + p1) + (p2 + p3);
                pf[nt] = pack_bf4(p0, p1, p2, p3);
            }

            __builtin_amdgcn_s_setprio(1);
#pragma unroll
            for (int ht = 0; ht < 4; ++ht) {
                short4v vf = *(const short4v*)(vtp + ht * 1024 + ln15 * 64
                               + (((kt * 2 + vch0) ^ xk) * 8) + vsub);
#pragma unroll
                for (int nt = 0; nt < 2; ++nt)
                    oacc[ht][nt] = __builtin_amdgcn_mfma_f32_16x16x16bf16_1k(
                        vf, pf[nt], oacc[ht][nt], 0, 0, 0);
            }
            __builtin_amdgcn_s_setprio(0);
        }

        // write next tile to the other LDS buffer
        if (tt < 15) {
            u16* ktn = &smem[(buf ^ 1) * 2 + 0][0];
            u16* vtn = &smem[(buf ^ 1) * 2 + 1][0];
            *(uint4*)(ktn + sw0) = ka;
            *(uint4*)(ktn + sw1) = kb4;
            *(uint4*)(vtn + sw0) = va;
            *(uint4*)(vtn + sw1) = vb4;
        }
        __syncthreads();
    }

    // ---- epilogue: in-wave l reduce, direct po write (no cross-wave O) ----
#pragma unroll
    for (int nt = 0; nt < 2; ++nt) {
        lacc[nt] += __shfl_xor(lacc[nt], 16);
        lacc[nt] += __shfl_xor(lacc[nt], 32);
    }
    if (lq == 0) {
#pragma unroll
        for (int nt = 0; nt < 2; ++nt)
            pml[(size_t)part * 128 + wave * 32 + nt * 16 + ln15] = lacc[nt];
    }

    // po[part][q][h], q = wave*32+nt*16+ln15, h = ht*16+lq*4+r (float4 stores)
    float* __restrict__ pob = po + (size_t)part * 8192;
#pragma unroll
    for (int ht = 0; ht < 4; ++ht)
#pragma unroll
        for (int nt = 0; nt < 2; ++nt)
            *(floatx4*)&pob[(wave * 32 + nt * 16 + ln15) * 64 + ht * 16 + lq * 4] = oacc[ht][nt];
}

// ---------------- split reduction: sum 4 splits, normalize (pure f4 stream) -------
__global__ __launch_bounds__(256) void reduce_kernel(
    const float* __restrict__ po, const float* __restrict__ pml,
    float* __restrict__ out) {
    __shared__ float ls[128];
    const int t = threadIdx.x;
    const int bq = blockIdx.x >> 1;      // 0..127: b = bq>>5, qblk = bq&31
    const int half = blockIdx.x & 1;
    const int part0 = bq * 4;

    if (t < 128)
        ls[t] = pml[(size_t)(part0 + 0) * 128 + t] + pml[(size_t)(part0 + 1) * 128 + t]
              + pml[(size_t)(part0 + 2) * 128 + t] + pml[(size_t)(part0 + 3) * 128 + t];
    __syncthreads();

    const float* __restrict__ p0 = po + (size_t)(part0 + 0) * 8192;
    const float* __restrict__ p1 = po + (size_t)(part0 + 1) * 8192;
    const float* __restrict__ p2 = po + (size_t)(part0 + 2) * 8192;
    const float* __restrict__ p3 = po + (size_t)(part0 + 3) * 8192;
    float* __restrict__ ob = out + ((size_t)(bq >> 5) * SEQ + (size_t)(bq & 31) * 128) * HD;

#pragma unroll
    for (int i = 0; i < 4; ++i) {
        int f4 = half * 1024 + t + i * 256;   // 0..2047
        int f = f4 * 4;
        int q = f4 >> 4;
        float4 a = *(const float4*)&p0[f];
        float4 c = *(const float4*)&p1[f];
        float4 d = *(const float4*)&p2[f];
        float4 e = *(const float4*)&p3[f];
        float inv = 1.0f / ls[q];
        float4 r;
        r.x = (a.x + c.x + d.x + e.x) * inv;
        r.y = (a.y + c.y + d.y + e.y) * inv;
        r.z = (a.z + c.z + d.z + e.z) * inv;
        r.w = (a.w + c.w + d.w + e.w) * inv;
        *(float4*)&ob[f] = r;
    }
}

extern "C" void kernel_launch(void* const* d_in, const int* in_sizes, int n_in,
                              void* d_out, int out_size, void* d_ws, size_t ws_size,
                              hipStream_t stream) {
    const float* emb = (const float*)d_in[0];
    const float* wk  = (const float*)d_in[1];
    const float* wq  = (const float*)d_in[2];
    const float* wv  = (const float*)d_in[3];

    // ws: qb 2M @0, kb 2M @2M, vbt 2M @4M, wt 96K @6M, po 16M @6.25M, pml 256K @22.25M
    u16* qb  = (u16*)d_ws;
    u16* kb  = (u16*)((char*)d_ws + (size_t)2 * 1024 * 1024);
    u16* vbt = (u16*)((char*)d_ws + (size_t)4 * 1024 * 1024);
    u16* wt  = (u16*)((char*)d_ws + (size_t)6 * 1024 * 1024);
    float* po  = (float*)((char*)d_ws + (size_t)6 * 1024 * 1024 + 256 * 1024);
    float* pml = (float*)((char*)d_ws + (size_t)22 * 1024 * 1024 + 256 * 1024);
    float* out = (float*)d_out;

    prep_w<<<12, 256, 0, stream>>>(wk, wq, wv, wt);
    proj_mfma<<<1024, 256, 0, stream>>>(emb, wt, qb, kb, vbt);
    attn_kernel<<<512, 256, 0, stream>>>(qb, kb, vbt, po, pml);
    reduce_kernel<<<256, 256, 0, stream>>>(po, pml, out);
}

// Round 9
// 111.632 us; speedup vs baseline: 1.0702x; 1.0271x over previous
//
#include <hip/hip_runtime.h>

// SA_Head: B=4, S=4096, E=256, H=64
//   out = softmax((emb@wq)(emb@wk)^T / 16) (emb@wv)
// R13: proj-only change (attn/prep/reduce = R12 verbatim). proj's epilogue
// was scalar-2B-store bound: Q/K written as 8 scalar u16 stores/lane, vbt
// as strided 8B stores. Now: 32 rows/block (grid 512), results staged to
// LDS ot[12][32][16], then coalesced 16B stores: Q/K as [row][64] ushort8
// stream, V gathered to ushort8 (8 s contiguous in vbt[h][s]).
// (R12: 128q attn blocks, all-keys-per-wave, no cross-wave O reduce,
//  LDS-staged K/V with chunk^=row&7 swizzle, split-K x4 grid 512.
//  Base: XCD swizzle, no-max softmax |s|<=4, S^T-form QK keeps P in
//  registers, V pre-transposed vbt[h][s].)

typedef short short4v __attribute__((ext_vector_type(4)));
typedef short short8v __attribute__((ext_vector_type(8)));
typedef unsigned short ushort8v __attribute__((ext_vector_type(8)));
typedef float floatx4 __attribute__((ext_vector_type(4)));
typedef unsigned short u16;
typedef unsigned int u32;

#define SEQ 4096
#define EMB 256
#define HD 64
#define PADA 264   // u16 stride for proj A tile

static __device__ __forceinline__ u16 f2bf(float x) {
    union { float f; unsigned u; } v; v.f = x;
    unsigned r = v.u + 0x7FFFu + ((v.u >> 16) & 1u);
    return (u16)(r >> 16);
}

static __device__ __forceinline__ u32 cvt_pk_bf16(float a, float b) {
    u32 r;
    asm("v_cvt_pk_bf16_f32 %0, %1, %2" : "=v"(r) : "v"(a), "v"(b));
    return r;
}

static __device__ __forceinline__ short4v pack_bf4(float a, float b, float c, float d) {
    union { u32 u[2]; short4v s; } x;
    x.u[0] = cvt_pk_bf16(a, b);
    x.u[1] = cvt_pk_bf16(c, d);
    return x.s;
}

// ---------------- W prep: fragment-major Wt --------------------------------------
__global__ __launch_bounds__(256) void prep_w(
    const float* __restrict__ wk, const float* __restrict__ wq, const float* __restrict__ wv,
    u16* __restrict__ wt) {
    const int nt = blockIdx.x;   // 0..11
    const int t = threadIdx.x;
#pragma unroll
    for (int ss = 0; ss < 2; ++ss) {
        int slot = t + ss * 256;          // 0..511
        int kc = slot >> 6, lane = slot & 63;
        int ln15 = lane & 15, lq = lane >> 4;
        int cg = nt * 16 + ln15;
        int mat = cg >> 6, col = cg & 63;
        const float* W = (mat == 0) ? wq : (mat == 1) ? wk : wv;
        const float s = (mat == 0) ? 0.0625f * 1.44269504088896f : 1.0f;
        u32 w4[4];
#pragma unroll
        for (int p = 0; p < 2; ++p) {
#pragma unroll
            for (int d = 0; d < 2; ++d) {
                int e0 = kc * 32 + lq * 8 + p * 4 + d * 2;
                u16 lo = f2bf(W[(e0 + 0) * HD + col] * s);
                u16 hi = f2bf(W[(e0 + 1) * HD + col] * s);
                w4[p * 2 + d] = (u32)lo | ((u32)hi << 16);
            }
        }
        u32* dst = (u32*)wt + ((size_t)(nt * 8 + kc) * 64 + lane) * 4;
        *(uint4*)dst = make_uint4(w4[0], w4[1], w4[2], w4[3]);
    }
}

// ---------------- projection GEMM: [16384,256]@[256,192] bf16 MFMA ----------------
// grid 512 x 256; 32 rows/block; wave w covers column-tiles 3w..3w+2 for
// both 16-row groups.  Epilogue: acc -> LDS ot[12][32][16] -> coalesced
// 16B stores (Q/K row-stream, V gathered per-h into vbt[h][s]).
__global__ __launch_bounds__(256) void proj_mfma(
    const float* __restrict__ emb, const u16* __restrict__ wt,
    u16* __restrict__ qb, u16* __restrict__ kb, u16* __restrict__ vbt) {
    __shared__ u16 a_s[32 * PADA];
    __shared__ __align__(16) u16 ot_s[12][32][16];
    const int t = threadIdx.x;
    const int lane = t & 63;
    const int wave = t >> 6;
    const int ln15 = lane & 15;
    const int lq = lane >> 4;
    const size_t row0 = (size_t)blockIdx.x * 32;

    // coalesced staging: flat float4 f = t + c*256 -> row f>>6, cols (f&63)*4
#pragma unroll
    for (int c = 0; c < 8; ++c) {
        int f = t + c * 256;
        int row = f >> 6, e4 = (f & 63) * 4;
        float4 v = *(const float4*)(emb + (row0 + row) * EMB + e4);
        u32 lo = cvt_pk_bf16(v.x, v.y);
        u32 hi = cvt_pk_bf16(v.z, v.w);
        *(uint2*)&a_s[row * PADA + e4] = make_uint2(lo, hi);
    }
    __syncthreads();

    floatx4 acc[2][3];
#pragma unroll
    for (int rg = 0; rg < 2; ++rg)
#pragma unroll
        for (int j = 0; j < 3; ++j) {
            floatx4 z = { 0.f, 0.f, 0.f, 0.f };
            acc[rg][j] = z;
        }

#pragma unroll
    for (int kc = 0; kc < 8; ++kc) {
        short8v a0 = *(const short8v*)&a_s[ln15 * PADA + kc * 32 + lq * 8];
        short8v a1 = *(const short8v*)&a_s[(16 + ln15) * PADA + kc * 32 + lq * 8];
#pragma unroll
        for (int j = 0; j < 3; ++j) {
            short8v b = *(const short8v*)(wt + (((size_t)(wave * 3 + j) * 8 + kc) * 64 + lane) * 8);
            acc[0][j] = __builtin_amdgcn_mfma_f32_16x16x32_bf16(a0, b, acc[0][j], 0, 0, 0);
            acc[1][j] = __builtin_amdgcn_mfma_f32_16x16x32_bf16(a1, b, acc[1][j], 0, 0, 0);
        }
    }

    // stage results to LDS: ot[tile][row][col16]
#pragma unroll
    for (int rg = 0; rg < 2; ++rg)
#pragma unroll
        for (int j = 0; j < 3; ++j)
#pragma unroll
            for (int r = 0; r < 4; ++r)
                ot_s[wave * 3 + j][rg * 16 + lq * 4 + r][ln15] = f2bf(acc[rg][j][r]);
    __syncthreads();

    // Q/K: [row][64] stream -- thread f: row=f>>3, chunk=f&7; one b128
    // ds_read (tile=chunk>>1, off=(chunk&1)*8) + one 16B global store.
    {
        const int row = t >> 3, chunk = t & 7;
        const int tile = chunk >> 1, off = (chunk & 1) * 8;
        ushort8v qv = *(const ushort8v*)&ot_s[tile][row][off];
        *(ushort8v*)&qb[(row0 + row) * HD + chunk * 8] = qv;
        ushort8v kv = *(const ushort8v*)&ot_s[4 + tile][row][off];
        *(ushort8v*)&kb[(row0 + row) * HD + chunk * 8] = kv;
    }
    // V: thread f: h=f>>2, sc=f&3; gather 8 s-values (column of ot) ->
    // one 16B store to vbt[(b*64+h)*4096 + sl0 + sc*8].
    {
        const int h = t >> 2, sc = t & 3;
        const int tile = 8 + (h >> 4), tcol = h & 15;
        union { u16 u[8]; ushort8v v; } g;
#pragma unroll
        for (int i = 0; i < 8; ++i)
            g.u[i] = ot_s[tile][sc * 8 + i][tcol];
        size_t bidx = row0 >> 12;
        size_t sl = (row0 & 4095) + sc * 8;
        *(ushort8v*)&vbt[(bidx * 64 + h) * SEQ + sl] = g.v;
    }
}

// ---------------- flash attention: LDS-staged tiles, 128q blocks, split-K x4 ------
// part = b*128 + qblk*4 + split; 4 waves; wave w owns q [q0+32w, +32) and
// ALL 64 keys of each staged tile.  Per tt: K[64k][64d], V^T[64h][64k] in
// LDS (coalesced, chunk^=row&7 swizzle); per 16-key subtile kt:
// S^T = K.Q^T (16x16x32), P = exp2 in-reg, O^T += V^T.P (16x16x16).
// No cross-wave O reduce: wave writes its finished 32q x 64h to po.

__global__ __launch_bounds__(256) void attn_kernel(
    const u16* __restrict__ qb, const u16* __restrict__ kb, const u16* __restrict__ vbt,
    float* __restrict__ po, float* __restrict__ pml) {
    __shared__ __align__(16) u16 smem[4][64 * 64];   // [buf*2+{K,V}][64 rows x 128B]

    const int t = threadIdx.x;
    const int lane = t & 63;
    const int wave = t >> 6;
    const int ln15 = lane & 15;
    const int lq = lane >> 4;

    // XCD-aware swizzle (512 blocks, 512%8==0 -> bijective)
    const int part = ((blockIdx.x & 7) << 6) | (blockIdx.x >> 3);
    const int b = part >> 7;
    const int qblk = (part >> 2) & 31;
    const int split = part & 3;
    const int q0 = qblk * 128;

    const u16* __restrict__ qpb = qb + ((size_t)b * SEQ + q0) * HD;
    const u16* __restrict__ kpb = kb + (size_t)b * SEQ * HD;
    const u16* __restrict__ vpb = vbt + (size_t)b * HD * SEQ;

    // Q B-frags (loop-invariant): wave's q rows = q0 + wave*32 + nt*16 + ln15
    short8v qf[2][2];
#pragma unroll
    for (int nt = 0; nt < 2; ++nt)
#pragma unroll
        for (int h = 0; h < 2; ++h)
            qf[nt][h] = *(const short8v*)(qpb + (size_t)(wave * 32 + nt * 16 + ln15) * HD + h * 32 + lq * 8);

    floatx4 oacc[4][2];
#pragma unroll
    for (int ht = 0; ht < 4; ++ht)
#pragma unroll
        for (int nt = 0; nt < 2; ++nt) {
            floatx4 z = { 0.f, 0.f, 0.f, 0.f };
            oacc[ht][nt] = z;
        }
    float lacc[2] = { 0.f, 0.f };

    // staging geometry: flat f = t (+256): row = f>>3, chunk = f&7 (16B units).
    const int r0 = t >> 3, c0 = t & 7, r1 = r0 + 32;
    const int sw0 = r0 * 64 + ((c0 ^ (r0 & 7)) * 8);
    const int sw1 = r1 * 64 + ((c0 ^ (r1 & 7)) * 8);

    // frag read offsets (u16 units); kt adds kt*1024 (rows) / chunk kt*2 (V)
    const int xk = ln15 & 7;
    const int ksw_lo = ln15 * 64 + ((lq ^ xk) * 8);
    const int ksw_hi = ln15 * 64 + (((4 + lq) ^ xk) * 8);
    const int vch0 = lq >> 1, vsub = (lq & 1) * 4;

    uint4 ka, kb4, va, vb4;
    {   // prologue: stage tile 0 into buf 0
        const int kwb = (split * 16) * 64;
        ka  = *(const uint4*)(kpb + (size_t)(kwb + r0) * HD + c0 * 8);
        kb4 = *(const uint4*)(kpb + (size_t)(kwb + r1) * HD + c0 * 8);
        va  = *(const uint4*)(vpb + (size_t)r0 * SEQ + kwb + c0 * 8);
        vb4 = *(const uint4*)(vpb + (size_t)r1 * SEQ + kwb + c0 * 8);
        *(uint4*)(&smem[0][0] + sw0) = ka;
        *(uint4*)(&smem[0][0] + sw1) = kb4;
        *(uint4*)(&smem[1][0] + sw0) = va;
        *(uint4*)(&smem[1][0] + sw1) = vb4;
    }
    __syncthreads();

#pragma unroll 1
    for (int tt = 0; tt < 16; ++tt) {
        const int buf = tt & 1;
        // issue next tile's global loads (latency hidden under compute)
        if (tt < 15) {
            const int kwb = (split * 16 + tt + 1) * 64;
            ka  = *(const uint4*)(kpb + (size_t)(kwb + r0) * HD + c0 * 8);
            kb4 = *(const uint4*)(kpb + (size_t)(kwb + r1) * HD + c0 * 8);
            va  = *(const uint4*)(vpb + (size_t)r0 * SEQ + kwb + c0 * 8);
            vb4 = *(const uint4*)(vpb + (size_t)r1 * SEQ + kwb + c0 * 8);
        }

        const u16* ktp = &smem[buf * 2 + 0][0];
        const u16* vtp = &smem[buf * 2 + 1][0];

        // 4 x 16-key subtiles; wave covers all of them for its 32 q
#pragma unroll
        for (int kt = 0; kt < 4; ++kt) {
            short8v k0 = *(const short8v*)(ktp + kt * 1024 + ksw_lo);
            short8v k1 = *(const short8v*)(ktp + kt * 1024 + ksw_hi);

            floatx4 s[2];
            __builtin_amdgcn_s_setprio(1);
#pragma unroll
            for (int nt = 0; nt < 2; ++nt) {
                floatx4 z = { 0.f, 0.f, 0.f, 0.f };
                s[nt] = __builtin_amdgcn_mfma_f32_16x16x32_bf16(k0, qf[nt][0], z, 0, 0, 0);
                s[nt] = __builtin_amdgcn_mfma_f32_16x16x32_bf16(k1, qf[nt][1], s[nt], 0, 0, 0);
            }
            __builtin_amdgcn_s_setprio(0);

            short4v pf[2];
#pragma unroll
            for (int nt = 0; nt < 2; ++nt) {
                float p0 = __builtin_amdgcn_exp2f(s[nt][0]);
                float p1 = __builtin_amdgcn_exp2f(s[nt][1]);
                float p2 = __builtin_amdgcn_exp2f(s[nt][2]);
                float p3 = __builtin_amdgcn_exp2f(s[nt][3]);
                lacc[nt] += (p0 + p1) + (p2 + p3);
                pf[nt] = pack_bf4(p0, p1, p2, p3);
            }

            __builtin_amdgcn_s_setprio(1);
#pragma unroll
            for (int ht = 0; ht < 4; ++ht) {
                short4v vf = *(const short4v*)(vtp + ht * 1024 + ln15 * 64
                               + (((kt * 2 + vch0) ^ xk) * 8) + vsub);
#pragma unroll
                for (int nt = 0; nt < 2; ++nt)
                    oacc[ht][nt] = __builtin_amdgcn_mfma_f32_16x16x16bf16_1k(
                        vf, pf[nt], oacc[ht][nt], 0, 0, 0);
            }
            __builtin_amdgcn_s_setprio(0);
        }

        // write next tile to the other LDS buffer
        if (tt < 15) {
            u16* ktn = &smem[(buf ^ 1) * 2 + 0][0];
            u16* vtn = &smem[(buf ^ 1) * 2 + 1][0];
            *(uint4*)(ktn + sw0) = ka;
            *(uint4*)(ktn + sw1) = kb4;
            *(uint4*)(vtn + sw0) = va;
            *(uint4*)(vtn + sw1) = vb4;
        }
        __syncthreads();
    }

    // ---- epilogue: in-wave l reduce, direct po write (no cross-wave O) ----
#pragma unroll
    for (int nt = 0; nt < 2; ++nt) {
        lacc[nt] += __shfl_xor(lacc[nt], 16);
        lacc[nt] += __shfl_xor(lacc[nt], 32);
    }
    if (lq == 0) {
#pragma unroll
        for (int nt = 0; nt < 2; ++nt)
            pml[(size_t)part * 128 + wave * 32 + nt * 16 + ln15] = lacc[nt];
    }

    // po[part][q][h], q = wave*32+nt*16+ln15, h = ht*16+lq*4+r (float4 stores)
    float* __restrict__ pob = po + (size_t)part * 8192;
#pragma unroll
    for (int ht = 0; ht < 4; ++ht)
#pragma unroll
        for (int nt = 0; nt < 2; ++nt)
            *(floatx4*)&pob[(wave * 32 + nt * 16 + ln15) * 64 + ht * 16 + lq * 4] = oacc[ht][nt];
}

// ---------------- split reduction: sum 4 splits, normalize (pure f4 stream) -------
__global__ __launch_bounds__(256) void reduce_kernel(
    const float* __restrict__ po, const float* __restrict__ pml,
    float* __restrict__ out) {
    __shared__ float ls[128];
    const int t = threadIdx.x;
    const int bq = blockIdx.x >> 1;      // 0..127: b = bq>>5, qblk = bq&31
    const int half = blockIdx.x & 1;
    const int part0 = bq * 4;

    if (t < 128)
        ls[t] = pml[(size_t)(part0 + 0) * 128 + t] + pml[(size_t)(part0 + 1) * 128 + t]
              + pml[(size_t)(part0 + 2) * 128 + t] + pml[(size_t)(part0 + 3) * 128 + t];
    __syncthreads();

    const float* __restrict__ p0 = po + (size_t)(part0 + 0) * 8192;
    const float* __restrict__ p1 = po + (size_t)(part0 + 1) * 8192;
    const float* __restrict__ p2 = po + (size_t)(part0 + 2) * 8192;
    const float* __restrict__ p3 = po + (size_t)(part0 + 3) * 8192;
    float* __restrict__ ob = out + ((size_t)(bq >> 5) * SEQ + (size_t)(bq & 31) * 128) * HD;

#pragma unroll
    for (int i = 0; i < 4; ++i) {
        int f4 = half * 1024 + t + i * 256;   // 0..2047
        int f = f4 * 4;
        int q = f4 >> 4;
        float4 a = *(const float4*)&p0[f];
        float4 c = *(const float4*)&p1[f];
        float4 d = *(const float4*)&p2[f];
        float4 e = *(const float4*)&p3[f];
        float inv = 1.0f / ls[q];
        float4 r;
        r.x = (a.x + c.x + d.x + e.x) * inv;
        r.y = (a.y + c.y + d.y + e.y) * inv;
        r.z = (a.z + c.z + d.z + e.z) * inv;
        r.w = (a.w + c.w + d.w + e.w) * inv;
        *(float4*)&ob[f] = r;
    }
}

extern "C" void kernel_launch(void* const* d_in, const int* in_sizes, int n_in,
                              void* d_out, int out_size, void* d_ws, size_t ws_size,
                              hipStream_t stream) {
    const float* emb = (const float*)d_in[0];
    const float* wk  = (const float*)d_in[1];
    const float* wq  = (const float*)d_in[2];
    const float* wv  = (const float*)d_in[3];

    // ws: qb 2M @0, kb 2M @2M, vbt 2M @4M, wt 96K @6M, po 16M @6.25M, pml 256K @22.25M
    u16* qb  = (u16*)d_ws;
    u16* kb  = (u16*)((char*)d_ws + (size_t)2 * 1024 * 1024);
    u16* vbt = (u16*)((char*)d_ws + (size_t)4 * 1024 * 1024);
    u16* wt  = (u16*)((char*)d_ws + (size_t)6 * 1024 * 1024);
    float* po  = (float*)((char*)d_ws + (size_t)6 * 1024 * 1024 + 256 * 1024);
    float* pml = (float*)((char*)d_ws + (size_t)22 * 1024 * 1024 + 256 * 1024);
    float* out = (float*)d_out;

    prep_w<<<12, 256, 0, stream>>>(wk, wq, wv, wt);
    proj_mfma<<<512, 256, 0, stream>>>(emb, wt, qb, kb, vbt);
    attn_kernel<<<512, 256, 0, stream>>>(qb, kb, vbt, po, pml);
    reduce_kernel<<<256, 256, 0, stream>>>(po, pml, out);
}